// Round 6
// baseline (308.315 us; speedup 1.0000x reference)
//
#include <hip/hip_runtime.h>
#include <hip/hip_bf16.h>

#define N_NODES 100000
#define N_EDGES 1600000
#define N_AGENTS 1000
#define NSUB 16

#define SCAN_BLOCK 256
#define N_SCAN_BLOCKS ((N_NODES + SCAN_BLOCK - 1) / SCAN_BLOCK)   // 391
#define AGG_BLOCKS 2048

typedef short s16x8 __attribute__((ext_vector_type(8)));
typedef float f32x4 __attribute__((ext_vector_type(4)));

// float -> bf16 round-to-nearest-even
__device__ __forceinline__ unsigned short f2bf(float f) {
    unsigned u = __float_as_uint(f);
    u += 0x7fffu + ((u >> 16) & 1u);
    return (unsigned short)(u >> 16);
}
__device__ __forceinline__ float bflo(unsigned u) { return __uint_as_float(u << 16); }
__device__ __forceinline__ float bfhi(unsigned u) { return __uint_as_float(u & 0xffff0000u); }

// ---------------- degree + replica-local rank ----------------
// Atomics spread over NSUB replica regions (sub = e & 15): 16x more distinct
// cache lines at the memory-side atomic unit -> 16x line parallelism.
__global__ void degree_rank_kernel(const int* __restrict__ dst, int* __restrict__ cnt_r,
                                   int* __restrict__ rank) {
    int base = (blockIdx.x * blockDim.x + threadIdx.x) * 4;
    if (base + 3 < N_EDGES) {
        int4 d = *(const int4*)(dst + base);
        int r0 = atomicAdd(&cnt_r[((base + 0) & (NSUB - 1)) * N_NODES + d.x], 1);
        int r1 = atomicAdd(&cnt_r[((base + 1) & (NSUB - 1)) * N_NODES + d.y], 1);
        int r2 = atomicAdd(&cnt_r[((base + 2) & (NSUB - 1)) * N_NODES + d.z], 1);
        int r3 = atomicAdd(&cnt_r[((base + 3) & (NSUB - 1)) * N_NODES + d.w], 1);
        *(int4*)(rank + base) = make_int4(r0, r1, r2, r3);
    } else if (base < N_EDGES) {
        for (int e = base; e < N_EDGES; e++)
            rank[e] = atomicAdd(&cnt_r[(e & (NSUB - 1)) * N_NODES + dst[e]], 1);
    }
}

// ---------------- scan pass 1: sum replicas, per-block exclusive scan ----------------
__global__ void scan1_kernel(const int* __restrict__ cnt_r, int* __restrict__ rowptr,
                             int* __restrict__ bsum) {
    __shared__ int tmp[SCAN_BLOCK];
    int i = blockIdx.x * SCAN_BLOCK + threadIdx.x;
    int v = 0;
    if (i < N_NODES) {
        #pragma unroll
        for (int s = 0; s < NSUB; s++) v += cnt_r[s * N_NODES + i];
    }
    tmp[threadIdx.x] = v;
    __syncthreads();
    for (int off = 1; off < SCAN_BLOCK; off <<= 1) {
        int u = (threadIdx.x >= off) ? tmp[threadIdx.x - off] : 0;
        __syncthreads();
        tmp[threadIdx.x] += u;
        __syncthreads();
    }
    if (i < N_NODES) rowptr[i] = tmp[threadIdx.x] - v;   // exclusive within block
    if (threadIdx.x == SCAN_BLOCK - 1) bsum[blockIdx.x] = tmp[SCAN_BLOCK - 1];
}

// ---------------- scan pass 2 ----------------
__global__ void scan2_kernel(int* __restrict__ bsum) {
    __shared__ int tmp[512];
    int t = threadIdx.x;
    int v = (t < N_SCAN_BLOCKS) ? bsum[t] : 0;
    tmp[t] = v;
    __syncthreads();
    for (int off = 1; off < 512; off <<= 1) {
        int u = (t >= off) ? tmp[t - off] : 0;
        __syncthreads();
        tmp[t] += u;
        __syncthreads();
    }
    if (t < N_SCAN_BLOCKS) bsum[t] = tmp[t] - v;
}

// ---------------- scan pass 3: finalize rowptr, inv-degree, per-(node,sub) bases ----------------
__global__ void scan3_kernel(const int* __restrict__ cnt_r, int* __restrict__ rowptr,
                             const int* __restrict__ bsum, float* __restrict__ inv,
                             int* __restrict__ basetab) {
    int i = blockIdx.x * SCAN_BLOCK + threadIdx.x;
    if (i == 0) rowptr[N_NODES] = N_EDGES;
    if (i >= N_NODES) return;
    int base = rowptr[i] + bsum[blockIdx.x];
    rowptr[i] = base;
    int start = base;
    #pragma unroll
    for (int s = 0; s < NSUB; s++) {
        basetab[i * NSUB + s] = base;
        base += cnt_r[s * N_NODES + i];
    }
    inv[i] = 1.0f / fmaxf((float)(base - start), 1.0f);
}

// ---------------- permute edges into CSR order (no atomics) ----------------
__global__ void permute_kernel(const int* __restrict__ src, const int* __restrict__ dst,
                               const int* __restrict__ rank, const int* __restrict__ basetab,
                               int* __restrict__ esrc) {
    int e = blockIdx.x * blockDim.x + threadIdx.x;
    if (e >= N_EDGES) return;
    int d = dst[e];
    esrc[basetab[d * NSUB + (e & (NSUB - 1))] + rank[e]] = src[e];
}

// ---------------- convert x (fp32) -> bf16 ----------------
__global__ void convert_x_kernel(const float* __restrict__ x, unsigned short* __restrict__ xb) {
    int i = blockIdx.x * blockDim.x + threadIdx.x;        // one float4 per thread
    if (i >= N_NODES * 32 / 4) return;
    float4 v = ((const float4*)x)[i];
    ushort4 o = make_ushort4(f2bf(v.x), f2bf(v.y), f2bf(v.z), f2bf(v.w));
    ((ushort4*)xb)[i] = o;
}

// ---------------- convert weights -> bf16, stacked [64 k][32 n] per layer ----------------
__global__ void prep_w_kernel(const float* __restrict__ Wl1, const float* __restrict__ Wr1,
                              const float* __restrict__ Wl2, const float* __restrict__ Wr2,
                              const float* __restrict__ Wl3, const float* __restrict__ Wr3,
                              unsigned short* __restrict__ Wcat) {
    int gid = blockIdx.x * blockDim.x + threadIdx.x;
    if (gid >= 3 * 2048) return;
    int L = gid >> 11, idx = gid & 2047;
    int k = idx >> 5, n = idx & 31;
    const float* Wl = (L == 0) ? Wl1 : (L == 1) ? Wl2 : Wl3;
    const float* Wr = (L == 0) ? Wr1 : (L == 1) ? Wr2 : Wr3;
    float v = (k < 32) ? Wl[k * 32 + n] : Wr[(k - 32) * 32 + n];
    Wcat[gid] = f2bf(v);
}

// ---------------- aggregate: mean of bf16 neighbor rows (fp32 acc) -> bf16 mean ----------------
// One wave per node; lane = (slot 0..7)*8 + (q 0..7); 8 neighbors in flight,
// each 64 B row gathered by 8 lanes as uint2 (8 B = 4 bf16 channels).
__global__ __launch_bounds__(256) void aggregate_kernel(
    const int* __restrict__ rowptr, const int* __restrict__ esrc,
    const float* __restrict__ inv, const unsigned short* __restrict__ hb,
    unsigned short* __restrict__ meanb, int n_nodes)
{
    int tid = threadIdx.x;
    int lane = tid & 63, wave = tid >> 6;
    int slot = lane >> 3, q = lane & 7;
    int stride = gridDim.x * 4;
    for (int node = blockIdx.x * 4 + wave; node < n_nodes; node += stride) {
        int beg = rowptr[node], end = rowptr[node + 1];
        float a0 = 0.f, a1 = 0.f, a2 = 0.f, a3 = 0.f;
        for (int j = beg + slot; j < end; j += 8) {
            int s = esrc[j];
            uint2 u = *(const uint2*)(hb + s * 32 + q * 4);
            a0 += bflo(u.x); a1 += bfhi(u.x);
            a2 += bflo(u.y); a3 += bfhi(u.y);
        }
        #pragma unroll
        for (int m = 8; m <= 32; m <<= 1) {
            a0 += __shfl_xor(a0, m);
            a1 += __shfl_xor(a1, m);
            a2 += __shfl_xor(a2, m);
            a3 += __shfl_xor(a3, m);
        }
        if (lane < 8) {   // lane == q: holds channels 4q..4q+3
            float iv = inv[node];
            ushort4 o = make_ushort4(f2bf(a0 * iv), f2bf(a1 * iv), f2bf(a2 * iv), f2bf(a3 * iv));
            *(ushort4*)(meanb + node * 32 + lane * 4) = o;   // 8 lanes x 8B = 64B coalesced
        }
    }
}

// ---------------- dense: out = relu(cat(mean,self) @ Wcat + b) via MFMA ----------------
// Wave computes a 16-node x 32-channel tile: 2 N-tiles x 2 K-steps = 4 MFMAs.
// A layout: A[m=lane&15][k=quad*8+j]; C/D: col=lane&15, row=quad*4+reg.
__global__ __launch_bounds__(256) void dense_kernel(
    const unsigned short* __restrict__ meanb, const unsigned short* __restrict__ selfb,
    const unsigned short* __restrict__ Wcat, const float* __restrict__ bl,
    void* __restrict__ outp, int n_nodes, int out_f32)
{
    int tid = threadIdx.x;
    int lane = tid & 63, wave = tid >> 6;
    int l15 = lane & 15, quad = lane >> 4;

    // B frags: B[k][n], lane holds n=lane&15 (+16*nt), k=quad*8+j (+32*kt)
    s16x8 bf[2][2];
    #pragma unroll
    for (int kt = 0; kt < 2; kt++)
        #pragma unroll
        for (int nt = 0; nt < 2; nt++)
            #pragma unroll
            for (int j = 0; j < 8; j++) {
                int k = kt * 32 + quad * 8 + j;
                bf[kt][nt][j] = (short)Wcat[k * 32 + l15 + nt * 16];
            }
    float bias0 = bl[l15], bias1 = bl[l15 + 16];

    int ntiles = (n_nodes + 15) >> 4;
    for (int tile = blockIdx.x * 4 + wave; tile < ntiles; tile += gridDim.x * 4) {
        int node = tile * 16 + l15;
        int na = min(node, n_nodes - 1);
        s16x8 am = *(const s16x8*)(meanb + na * 32 + quad * 8);
        s16x8 as = *(const s16x8*)(selfb + na * 32 + quad * 8);
        f32x4 acc0 = {0.f, 0.f, 0.f, 0.f};
        f32x4 acc1 = {0.f, 0.f, 0.f, 0.f};
        acc0 = __builtin_amdgcn_mfma_f32_16x16x32_bf16(am, bf[0][0], acc0, 0, 0, 0);
        acc0 = __builtin_amdgcn_mfma_f32_16x16x32_bf16(as, bf[1][0], acc0, 0, 0, 0);
        acc1 = __builtin_amdgcn_mfma_f32_16x16x32_bf16(am, bf[0][1], acc1, 0, 0, 0);
        acc1 = __builtin_amdgcn_mfma_f32_16x16x32_bf16(as, bf[1][1], acc1, 0, 0, 0);
        #pragma unroll
        for (int r = 0; r < 4; r++) {
            int onode = tile * 16 + quad * 4 + r;
            if (onode < n_nodes) {
                float v0 = fmaxf(acc0[r] + bias0, 0.f);
                float v1 = fmaxf(acc1[r] + bias1, 0.f);
                if (out_f32) {
                    ((float*)outp)[onode * 32 + l15]      = v0;
                    ((float*)outp)[onode * 32 + l15 + 16] = v1;
                } else {
                    ((unsigned short*)outp)[onode * 32 + l15]      = f2bf(v0);
                    ((unsigned short*)outp)[onode * 32 + l15 + 16] = f2bf(v1);
                }
            }
        }
    }
}

// ---------------- output projection: first 1000 nodes, 32 -> 8 (fp32) ----------------
__global__ void out_proj_kernel(const float* __restrict__ h3,
                                const float* __restrict__ Wout,
                                const float* __restrict__ bout,
                                float* __restrict__ out) {
    __shared__ float sWo[256];
    __shared__ float sbo[8];
    int tid = threadIdx.x;
    sWo[tid] = Wout[tid];
    if (tid < 8) sbo[tid] = bout[tid];
    __syncthreads();
    int node = blockIdx.x * 32 + (tid >> 3);
    int c = tid & 7;
    if (node >= N_AGENTS) return;
    float o = sbo[c];
    const float* hr = h3 + node * 32;
    #pragma unroll
    for (int k = 0; k < 32; k++) o += hr[k] * sWo[(k << 3) + c];
    out[node * 8 + c] = o;
}

extern "C" void kernel_launch(void* const* d_in, const int* in_sizes, int n_in,
                              void* d_out, int out_size, void* d_ws, size_t ws_size,
                              hipStream_t stream) {
    const float* x   = (const float*)d_in[0];
    const int* ei    = (const int*)d_in[1];
    const float* Wl1 = (const float*)d_in[2];
    const float* bl1 = (const float*)d_in[3];
    const float* Wr1 = (const float*)d_in[4];
    const float* Wl2 = (const float*)d_in[5];
    const float* bl2 = (const float*)d_in[6];
    const float* Wr2 = (const float*)d_in[7];
    const float* Wl3 = (const float*)d_in[8];
    const float* bl3 = (const float*)d_in[9];
    const float* Wr3 = (const float*)d_in[10];
    const float* Wout = (const float*)d_in[11];
    const float* bout = (const float*)d_in[12];
    float* out = (float*)d_out;

    const int* src = ei;
    const int* dst = ei + N_EDGES;

    // workspace layout (aliasing: cnt_r<->hAb, basetab<->hBb, rank<->meanb;
    // each alias pair has disjoint live ranges within one launch)
    char* ws = (char*)d_ws;
    int*   rowptr = (int*)ws;                                  ws += (size_t)(N_NODES + 8) * 4;
    float* inv    = (float*)ws;                                ws += (size_t)N_NODES * 4;
    int*   bsum   = (int*)ws;                                  ws += 512 * 4;
    int*   esrc   = (int*)ws;                                  ws += (size_t)N_EDGES * 4;
    unsigned short* meanb = (unsigned short*)ws;               ws += (size_t)N_NODES * 32 * 2;
    unsigned short* hXb   = (unsigned short*)ws;               ws += (size_t)N_NODES * 32 * 2;
    unsigned short* hAb   = (unsigned short*)ws;               ws += (size_t)N_NODES * 32 * 2;
    unsigned short* hBb   = (unsigned short*)ws;               ws += (size_t)N_NODES * 32 * 2;
    unsigned short* Wcat  = (unsigned short*)ws;               ws += 3 * 2048 * 2;
    float* h3f    = (float*)ws;                                ws += (size_t)N_AGENTS * 32 * 4;
    int*   rank    = (int*)meanb;   // dead before layer-1 aggregate writes meanb
    int*   cnt_r   = (int*)hAb;     // NSUB*N_NODES ints = 6.4MB; dead before dense-L1 writes hAb
    int*   basetab = (int*)hBb;     // NSUB*N_NODES ints = 6.4MB; dead before dense-L2 writes hBb

    // ---- input conversion (independent of CSR build) ----
    convert_x_kernel<<<(N_NODES * 32 / 4 + 255) / 256, 256, 0, stream>>>(x, hXb);
    prep_w_kernel<<<24, 256, 0, stream>>>(Wl1, Wr1, Wl2, Wr2, Wl3, Wr3, Wcat);

    // ---- CSR build ----
    hipMemsetAsync(cnt_r, 0, (size_t)NSUB * N_NODES * sizeof(int), stream);
    degree_rank_kernel<<<(N_EDGES / 4 + 255) / 256, 256, 0, stream>>>(dst, cnt_r, rank);
    scan1_kernel<<<N_SCAN_BLOCKS, SCAN_BLOCK, 0, stream>>>(cnt_r, rowptr, bsum);
    scan2_kernel<<<1, 512, 0, stream>>>(bsum);
    scan3_kernel<<<N_SCAN_BLOCKS, SCAN_BLOCK, 0, stream>>>(cnt_r, rowptr, bsum, inv, basetab);
    permute_kernel<<<(N_EDGES + 255) / 256, 256, 0, stream>>>(src, dst, rank, basetab, esrc);

    // ---- layer 1 ----
    aggregate_kernel<<<AGG_BLOCKS, 256, 0, stream>>>(rowptr, esrc, inv, hXb, meanb, N_NODES);
    dense_kernel<<<512, 256, 0, stream>>>(meanb, hXb, Wcat, bl1, hAb, N_NODES, 0);
    // ---- layer 2 ----
    aggregate_kernel<<<AGG_BLOCKS, 256, 0, stream>>>(rowptr, esrc, inv, hAb, meanb, N_NODES);
    dense_kernel<<<512, 256, 0, stream>>>(meanb, hAb, Wcat + 2048, bl2, hBb, N_NODES, 0);
    // ---- layer 3: only nodes < N_AGENTS needed ----
    aggregate_kernel<<<(N_AGENTS + 3) / 4, 256, 0, stream>>>(rowptr, esrc, inv, hBb, meanb, N_AGENTS);
    dense_kernel<<<16, 256, 0, stream>>>(meanb, hBb, Wcat + 4096, bl3, h3f, N_AGENTS, 1);
    out_proj_kernel<<<(N_AGENTS + 31) / 32, 256, 0, stream>>>(h3f, Wout, bout, out);
}

// Round 7
// 280.242 us; speedup vs baseline: 1.1002x; 1.1002x over previous
//
#include <hip/hip_runtime.h>
#include <hip/hip_bf16.h>

#define N_NODES 100000
#define N_EDGES 1600000
#define N_AGENTS 1000

#define SCAN_BLOCK 256
#define N_SCAN_BLOCKS ((N_NODES + SCAN_BLOCK - 1) / SCAN_BLOCK)   // 391
#define CONV_BLOCKS 3125   // 800000 ushort4 elements / 256

typedef short s16x8 __attribute__((ext_vector_type(8)));
typedef float f32x4 __attribute__((ext_vector_type(4)));

// float -> bf16 round-to-nearest-even
__device__ __forceinline__ unsigned short f2bf(float f) {
    unsigned u = __float_as_uint(f);
    u += 0x7fffu + ((u >> 16) & 1u);
    return (unsigned short)(u >> 16);
}
__device__ __forceinline__ float bflo(unsigned u) { return __uint_as_float(u << 16); }
__device__ __forceinline__ float bfhi(unsigned u) { return __uint_as_float(u & 0xffff0000u); }

// ---------------- degree + per-edge rank (atomic wall: ~24 G random RMW/s) ----------------
__global__ void degree_rank_kernel(const int* __restrict__ dst, int* __restrict__ cnt,
                                   int* __restrict__ rank) {
    int e = blockIdx.x * blockDim.x + threadIdx.x;
    if (e < N_EDGES) rank[e] = atomicAdd(&cnt[dst[e]], 1);
}

// ---------------- scan pass 1 ----------------
__global__ void scan1_kernel(const int* __restrict__ cnt, int* __restrict__ rowptr,
                             int* __restrict__ bsum) {
    __shared__ int tmp[SCAN_BLOCK];
    int i = blockIdx.x * SCAN_BLOCK + threadIdx.x;
    int v = (i < N_NODES) ? cnt[i] : 0;
    tmp[threadIdx.x] = v;
    __syncthreads();
    for (int off = 1; off < SCAN_BLOCK; off <<= 1) {
        int u = (threadIdx.x >= off) ? tmp[threadIdx.x - off] : 0;
        __syncthreads();
        tmp[threadIdx.x] += u;
        __syncthreads();
    }
    if (i < N_NODES) rowptr[i] = tmp[threadIdx.x] - v;
    if (threadIdx.x == SCAN_BLOCK - 1) bsum[blockIdx.x] = tmp[SCAN_BLOCK - 1];
}

// ---------------- scan pass 2 ----------------
__global__ void scan2_kernel(int* __restrict__ bsum) {
    __shared__ int tmp[512];
    int t = threadIdx.x;
    int v = (t < N_SCAN_BLOCKS) ? bsum[t] : 0;
    tmp[t] = v;
    __syncthreads();
    for (int off = 1; off < 512; off <<= 1) {
        int u = (t >= off) ? tmp[t - off] : 0;
        __syncthreads();
        tmp[t] += u;
        __syncthreads();
    }
    if (t < N_SCAN_BLOCKS) bsum[t] = tmp[t] - v;
}

// ---------------- scan pass 3: add offsets; emit inv-degree ----------------
__global__ void scan3_kernel(const int* __restrict__ cnt, int* __restrict__ rowptr,
                             const int* __restrict__ bsum, float* __restrict__ inv) {
    int i = blockIdx.x * SCAN_BLOCK + threadIdx.x;
    if (i == 0) rowptr[N_NODES] = N_EDGES;
    if (i >= N_NODES) return;
    rowptr[i] += bsum[blockIdx.x];
    inv[i] = 1.0f / fmaxf((float)cnt[i], 1.0f);
}

// ---------------- permute edges into CSR order: 4 edges/thread, no atomics ----------------
__global__ void permute_kernel(const int* __restrict__ src, const int* __restrict__ dst,
                               const int* __restrict__ rank, const int* __restrict__ rowptr,
                               int* __restrict__ esrc) {
    int base = (blockIdx.x * blockDim.x + threadIdx.x) * 4;
    if (base >= N_EDGES) return;
    int4 s = *(const int4*)(src + base);
    int4 d = *(const int4*)(dst + base);
    int4 r = *(const int4*)(rank + base);
    esrc[rowptr[d.x] + r.x] = s.x;
    esrc[rowptr[d.y] + r.y] = s.y;
    esrc[rowptr[d.z] + r.z] = s.z;
    esrc[rowptr[d.w] + r.w] = s.w;
}

// ---------------- prep: convert x -> bf16 AND weights -> bf16 [64k x 32n] ----------------
__global__ void prep_kernel(const float* __restrict__ x, unsigned short* __restrict__ xb,
                            const float* __restrict__ Wl1, const float* __restrict__ Wr1,
                            const float* __restrict__ Wl2, const float* __restrict__ Wr2,
                            const float* __restrict__ Wl3, const float* __restrict__ Wr3,
                            unsigned short* __restrict__ Wcat) {
    int b = blockIdx.x;
    if (b < CONV_BLOCKS) {
        int i = b * 256 + threadIdx.x;          // one float4 -> ushort4 per thread
        float4 v = ((const float4*)x)[i];       // 800000 elements, grid exact
        ((ushort4*)xb)[i] = make_ushort4(f2bf(v.x), f2bf(v.y), f2bf(v.z), f2bf(v.w));
    } else {
        int gid = (b - CONV_BLOCKS) * 256 + threadIdx.x;
        if (gid >= 3 * 2048) return;
        int L = gid >> 11, idx = gid & 2047;
        int k = idx >> 5, n = idx & 31;
        const float* Wl = (L == 0) ? Wl1 : (L == 1) ? Wl2 : Wl3;
        const float* Wr = (L == 0) ? Wr1 : (L == 1) ? Wr2 : Wr3;
        float v = (k < 32) ? Wl[k * 32 + n] : Wr[(k - 32) * 32 + n];
        Wcat[gid] = f2bf(v);
    }
}

// ---------------- aggregate: 4 lanes per node, 16 nodes per wave, no shuffles ----------------
// lane = g*4 + q: group g owns node, lane q holds channels 8q..8q+7 privately
// in fp32 regs. Each gather instr touches 16 distinct 64B rows; 2x unroll ->
// 32 rows in flight per wave. Store: wave writes 16 contiguous rows (1 KB).
__global__ __launch_bounds__(256) void aggregate_kernel(
    const int* __restrict__ rowptr, const int* __restrict__ esrc,
    const float* __restrict__ inv, const unsigned short* __restrict__ hb,
    unsigned short* __restrict__ meanb, int n_nodes)
{
    int tid = threadIdx.x;
    int lane = tid & 63, wave = tid >> 6;
    int g = lane >> 2, q = lane & 3;
    int node = (blockIdx.x * 4 + wave) * 16 + g;
    if (node >= n_nodes) return;
    int beg = rowptr[node], end = rowptr[node + 1];
    float a0 = 0.f, a1 = 0.f, a2 = 0.f, a3 = 0.f;
    float a4 = 0.f, a5 = 0.f, a6 = 0.f, a7 = 0.f;
    int j = beg;
    for (; j + 1 < end; j += 2) {
        int s0 = esrc[j];
        int s1 = esrc[j + 1];
        uint4 u0 = *(const uint4*)(hb + s0 * 32 + q * 8);
        uint4 u1 = *(const uint4*)(hb + s1 * 32 + q * 8);
        a0 += bflo(u0.x); a1 += bfhi(u0.x);
        a2 += bflo(u0.y); a3 += bfhi(u0.y);
        a4 += bflo(u0.z); a5 += bfhi(u0.z);
        a6 += bflo(u0.w); a7 += bfhi(u0.w);
        a0 += bflo(u1.x); a1 += bfhi(u1.x);
        a2 += bflo(u1.y); a3 += bfhi(u1.y);
        a4 += bflo(u1.z); a5 += bfhi(u1.z);
        a6 += bflo(u1.w); a7 += bfhi(u1.w);
    }
    if (j < end) {
        int s = esrc[j];
        uint4 u = *(const uint4*)(hb + s * 32 + q * 8);
        a0 += bflo(u.x); a1 += bfhi(u.x);
        a2 += bflo(u.y); a3 += bfhi(u.y);
        a4 += bflo(u.z); a5 += bfhi(u.z);
        a6 += bflo(u.w); a7 += bfhi(u.w);
    }
    float iv = inv[node];
    uint4 o;
    o.x = (unsigned)f2bf(a0 * iv) | ((unsigned)f2bf(a1 * iv) << 16);
    o.y = (unsigned)f2bf(a2 * iv) | ((unsigned)f2bf(a3 * iv) << 16);
    o.z = (unsigned)f2bf(a4 * iv) | ((unsigned)f2bf(a5 * iv) << 16);
    o.w = (unsigned)f2bf(a6 * iv) | ((unsigned)f2bf(a7 * iv) << 16);
    *(uint4*)(meanb + node * 32 + q * 8) = o;
}

// ---------------- dense: out = relu(cat(mean,self) @ Wcat + b) via MFMA ----------------
// Wave computes a 16-node x 32-channel tile: 2 N-tiles x 2 K-steps = 4 MFMAs.
// A layout: A[m=lane&15][k=quad*8+j]; C/D: col=lane&15, row=quad*4+reg.
__global__ __launch_bounds__(256) void dense_kernel(
    const unsigned short* __restrict__ meanb, const unsigned short* __restrict__ selfb,
    const unsigned short* __restrict__ Wcat, const float* __restrict__ bl,
    void* __restrict__ outp, int n_nodes, int out_f32)
{
    int tid = threadIdx.x;
    int lane = tid & 63, wave = tid >> 6;
    int l15 = lane & 15, quad = lane >> 4;

    // B frags: B[k][n], lane holds n=lane&15 (+16*nt), k=quad*8+j (+32*kt)
    s16x8 bf[2][2];
    #pragma unroll
    for (int kt = 0; kt < 2; kt++)
        #pragma unroll
        for (int nt = 0; nt < 2; nt++)
            #pragma unroll
            for (int j = 0; j < 8; j++) {
                int k = kt * 32 + quad * 8 + j;
                bf[kt][nt][j] = (short)Wcat[k * 32 + l15 + nt * 16];
            }
    float bias0 = bl[l15], bias1 = bl[l15 + 16];

    int ntiles = (n_nodes + 15) >> 4;
    for (int tile = blockIdx.x * 4 + wave; tile < ntiles; tile += gridDim.x * 4) {
        int node = tile * 16 + l15;
        int na = min(node, n_nodes - 1);
        s16x8 am = *(const s16x8*)(meanb + na * 32 + quad * 8);
        s16x8 as = *(const s16x8*)(selfb + na * 32 + quad * 8);
        f32x4 acc0 = {0.f, 0.f, 0.f, 0.f};
        f32x4 acc1 = {0.f, 0.f, 0.f, 0.f};
        acc0 = __builtin_amdgcn_mfma_f32_16x16x32_bf16(am, bf[0][0], acc0, 0, 0, 0);
        acc0 = __builtin_amdgcn_mfma_f32_16x16x32_bf16(as, bf[1][0], acc0, 0, 0, 0);
        acc1 = __builtin_amdgcn_mfma_f32_16x16x32_bf16(am, bf[0][1], acc1, 0, 0, 0);
        acc1 = __builtin_amdgcn_mfma_f32_16x16x32_bf16(as, bf[1][1], acc1, 0, 0, 0);
        #pragma unroll
        for (int r = 0; r < 4; r++) {
            int onode = tile * 16 + quad * 4 + r;
            if (onode < n_nodes) {
                float v0 = fmaxf(acc0[r] + bias0, 0.f);
                float v1 = fmaxf(acc1[r] + bias1, 0.f);
                if (out_f32) {
                    ((float*)outp)[onode * 32 + l15]      = v0;
                    ((float*)outp)[onode * 32 + l15 + 16] = v1;
                } else {
                    ((unsigned short*)outp)[onode * 32 + l15]      = f2bf(v0);
                    ((unsigned short*)outp)[onode * 32 + l15 + 16] = f2bf(v1);
                }
            }
        }
    }
}

// ---------------- output projection: first 1000 nodes, 32 -> 8 (fp32) ----------------
__global__ void out_proj_kernel(const float* __restrict__ h3,
                                const float* __restrict__ Wout,
                                const float* __restrict__ bout,
                                float* __restrict__ out) {
    __shared__ float sWo[256];
    __shared__ float sbo[8];
    int tid = threadIdx.x;
    sWo[tid] = Wout[tid];
    if (tid < 8) sbo[tid] = bout[tid];
    __syncthreads();
    int node = blockIdx.x * 32 + (tid >> 3);
    int c = tid & 7;
    if (node >= N_AGENTS) return;
    float o = sbo[c];
    const float* hr = h3 + node * 32;
    #pragma unroll
    for (int k = 0; k < 32; k++) o += hr[k] * sWo[(k << 3) + c];
    out[node * 8 + c] = o;
}

extern "C" void kernel_launch(void* const* d_in, const int* in_sizes, int n_in,
                              void* d_out, int out_size, void* d_ws, size_t ws_size,
                              hipStream_t stream) {
    const float* x   = (const float*)d_in[0];
    const int* ei    = (const int*)d_in[1];
    const float* Wl1 = (const float*)d_in[2];
    const float* bl1 = (const float*)d_in[3];
    const float* Wr1 = (const float*)d_in[4];
    const float* Wl2 = (const float*)d_in[5];
    const float* bl2 = (const float*)d_in[6];
    const float* Wr2 = (const float*)d_in[7];
    const float* Wl3 = (const float*)d_in[8];
    const float* bl3 = (const float*)d_in[9];
    const float* Wr3 = (const float*)d_in[10];
    const float* Wout = (const float*)d_in[11];
    const float* bout = (const float*)d_in[12];
    float* out = (float*)d_out;

    const int* src = ei;
    const int* dst = ei + N_EDGES;

    // workspace layout
    char* ws = (char*)d_ws;
    int*   cnt    = (int*)ws;                                  ws += (size_t)N_NODES * 4;
    int*   rowptr = (int*)ws;                                  ws += (size_t)(N_NODES + 8) * 4;
    float* inv    = (float*)ws;                                ws += (size_t)N_NODES * 4;
    int*   bsum   = (int*)ws;                                  ws += 512 * 4;
    int*   esrc   = (int*)ws;                                  ws += (size_t)N_EDGES * 4;
    unsigned short* meanb = (unsigned short*)ws;               ws += (size_t)N_NODES * 32 * 2;
    unsigned short* hXb   = (unsigned short*)ws;               ws += (size_t)N_NODES * 32 * 2;
    unsigned short* hAb   = (unsigned short*)ws;               ws += (size_t)N_NODES * 32 * 2;
    unsigned short* hBb   = (unsigned short*)ws;               ws += (size_t)N_NODES * 32 * 2;
    unsigned short* Wcat  = (unsigned short*)ws;               ws += 3 * 2048 * 2;
    float* h3f    = (float*)ws;                                ws += (size_t)N_AGENTS * 32 * 4;
    int*   rank   = (int*)meanb;   // 6.4MB alias: rank dead before layer-1 aggregate writes meanb

    // ---- input conversion (independent of CSR build) ----
    prep_kernel<<<CONV_BLOCKS + 24, 256, 0, stream>>>(x, hXb, Wl1, Wr1, Wl2, Wr2, Wl3, Wr3, Wcat);

    // ---- CSR build ----
    hipMemsetAsync(cnt, 0, N_NODES * sizeof(int), stream);
    degree_rank_kernel<<<(N_EDGES + 255) / 256, 256, 0, stream>>>(dst, cnt, rank);
    scan1_kernel<<<N_SCAN_BLOCKS, SCAN_BLOCK, 0, stream>>>(cnt, rowptr, bsum);
    scan2_kernel<<<1, 512, 0, stream>>>(bsum);
    scan3_kernel<<<N_SCAN_BLOCKS, SCAN_BLOCK, 0, stream>>>(cnt, rowptr, bsum, inv);
    permute_kernel<<<(N_EDGES / 4 + 255) / 256, 256, 0, stream>>>(src, dst, rank, rowptr, esrc);

    // ---- layer 1 ----
    aggregate_kernel<<<(N_NODES + 63) / 64, 256, 0, stream>>>(rowptr, esrc, inv, hXb, meanb, N_NODES);
    dense_kernel<<<512, 256, 0, stream>>>(meanb, hXb, Wcat, bl1, hAb, N_NODES, 0);
    // ---- layer 2 ----
    aggregate_kernel<<<(N_NODES + 63) / 64, 256, 0, stream>>>(rowptr, esrc, inv, hAb, meanb, N_NODES);
    dense_kernel<<<512, 256, 0, stream>>>(meanb, hAb, Wcat + 2048, bl2, hBb, N_NODES, 0);
    // ---- layer 3: only nodes < N_AGENTS needed ----
    aggregate_kernel<<<(N_AGENTS + 63) / 64, 256, 0, stream>>>(rowptr, esrc, inv, hBb, meanb, N_AGENTS);
    dense_kernel<<<16, 256, 0, stream>>>(meanb, hBb, Wcat + 4096, bl3, h3f, N_AGENTS, 1);
    out_proj_kernel<<<(N_AGENTS + 31) / 32, 256, 0, stream>>>(h3f, Wout, bout, out);
}

// Round 8
// 250.176 us; speedup vs baseline: 1.2324x; 1.1202x over previous
//
#include <hip/hip_runtime.h>
#include <hip/hip_bf16.h>

#define N_NODES 100000
#define N_EDGES 1600000
#define N_AGENTS 1000

#define NB 782                 // buckets of 128 nodes (782*128 = 100096 >= 100000)
#define ABLK 128               // edge-chunk blocks for histogram/scatter
#define CHUNK (N_EDGES / ABLK) // 12500 exactly
#define CONV_BLOCKS 3125       // 800000 float4->ushort4 elements / 256

typedef short s16x8 __attribute__((ext_vector_type(8)));
typedef float f32x4 __attribute__((ext_vector_type(4)));

// float -> bf16 round-to-nearest-even
__device__ __forceinline__ unsigned short f2bf(float f) {
    unsigned u = __float_as_uint(f);
    u += 0x7fffu + ((u >> 16) & 1u);
    return (unsigned short)(u >> 16);
}
__device__ __forceinline__ float bflo(unsigned u) { return __uint_as_float(u << 16); }
__device__ __forceinline__ float bfhi(unsigned u) { return __uint_as_float(u & 0xffff0000u); }

// ---------------- A: bucket histogram (LDS atomics only) + fused prep ----------------
__global__ __launch_bounds__(256) void hist_prep_kernel(
    const int* __restrict__ dst, int* __restrict__ partial,
    const float* __restrict__ x, unsigned short* __restrict__ xb,
    const float* __restrict__ Wl1, const float* __restrict__ Wr1,
    const float* __restrict__ Wl2, const float* __restrict__ Wr2,
    const float* __restrict__ Wl3, const float* __restrict__ Wr3,
    unsigned short* __restrict__ Wcat)
{
    int b = blockIdx.x;
    if (b < ABLK) {
        __shared__ int hist[NB];
        for (int i = threadIdx.x; i < NB; i += 256) hist[i] = 0;
        __syncthreads();
        int beg = b * CHUNK;
        for (int e = beg + threadIdx.x; e < beg + CHUNK; e += 256)
            atomicAdd(&hist[dst[e] >> 7], 1);            // LDS atomic
        __syncthreads();
        for (int i = threadIdx.x; i < NB; i += 256) partial[b * NB + i] = hist[i];
    } else if (b < ABLK + CONV_BLOCKS) {
        int i = (b - ABLK) * 256 + threadIdx.x;          // exact: 800000 elements
        float4 v = ((const float4*)x)[i];
        ((ushort4*)xb)[i] = make_ushort4(f2bf(v.x), f2bf(v.y), f2bf(v.z), f2bf(v.w));
    } else {
        int gid = (b - ABLK - CONV_BLOCKS) * 256 + threadIdx.x;
        if (gid >= 3 * 2048) return;
        int L = gid >> 11, idx = gid & 2047;
        int k = idx >> 5, n = idx & 31;
        const float* Wl = (L == 0) ? Wl1 : (L == 1) ? Wl2 : Wl3;
        const float* Wr = (L == 0) ? Wr1 : (L == 1) ? Wr2 : Wr3;
        float v = (k < 32) ? Wl[k * 32 + n] : Wr[(k - 32) * 32 + n];
        Wcat[gid] = f2bf(v);
    }
}

// ---------------- B: bucket totals -> exclusive scan -> per-(block,bucket) bases ----------------
__global__ __launch_bounds__(1024) void bucket_scan_kernel(
    const int* __restrict__ partial, int* __restrict__ base, int* __restrict__ bstart)
{
    __shared__ int tot[1024];
    int t = threadIdx.x;                 // bucket id
    int sum = 0;
    if (t < NB)
        for (int k = 0; k < ABLK; k++) sum += partial[k * NB + t];
    tot[t] = sum;
    __syncthreads();
    for (int off = 1; off < 1024; off <<= 1) {
        int u = (t >= off) ? tot[t - off] : 0;
        __syncthreads();
        tot[t] += u;
        __syncthreads();
    }
    int start = tot[t] - sum;            // exclusive
    if (t < NB) {
        bstart[t] = start;
        if (t == NB - 1) bstart[NB] = tot[t];   // == N_EDGES
        int run = start;
        for (int k = 0; k < ABLK; k++) {        // coalesced across lanes per k
            base[k * NB + t] = run;
            run += partial[k * NB + t];
        }
    }
}

// ---------------- C: scatter edges into buckets, packed (src | local_node<<17) ----------------
__global__ __launch_bounds__(256) void bucket_scatter_kernel(
    const int* __restrict__ src, const int* __restrict__ dst,
    const int* __restrict__ base, int* __restrict__ ebuf)
{
    __shared__ int cur[NB];
    int b = blockIdx.x;
    for (int i = threadIdx.x; i < NB; i += 256) cur[i] = base[b * NB + i];
    __syncthreads();
    int beg = b * CHUNK;
    for (int e = beg + threadIdx.x; e < beg + CHUNK; e += 256) {
        int d = dst[e];
        int slot = atomicAdd(&cur[d >> 7], 1);           // LDS atomic
        ebuf[slot] = src[e] | ((d & 127) << 17);         // src < 2^17
    }
}

// ---------------- D: per-bucket CSR finalize: rowptr, inv, node-exact esrc ----------------
__global__ __launch_bounds__(256) void bucket_csr_kernel(
    const int* __restrict__ bstart, const int* __restrict__ ebuf,
    int* __restrict__ rowptr, float* __restrict__ inv, int* __restrict__ esrc)
{
    __shared__ int hist[128], cur[128], tmp[256];
    int b = blockIdx.x;
    int t = threadIdx.x;
    int beg = bstart[b], end = bstart[b + 1];
    if (t < 128) hist[t] = 0;
    __syncthreads();
    for (int i = beg + t; i < end; i += 256)
        atomicAdd(&hist[(ebuf[i] >> 17) & 127], 1);      // LDS atomic
    __syncthreads();
    int v = (t < 128) ? hist[t] : 0;
    tmp[t] = v;
    __syncthreads();
    for (int off = 1; off < 256; off <<= 1) {
        int u = (t >= off) ? tmp[t - off] : 0;
        __syncthreads();
        tmp[t] += u;
        __syncthreads();
    }
    int excl = tmp[t] - v;                               // exclusive within bucket
    int node = b * 128 + t;
    if (t < 128 && node < N_NODES) {
        rowptr[node] = beg + excl;
        inv[node] = 1.0f / fmaxf((float)v, 1.0f);
        cur[t] = beg + excl;
    }
    if (b == NB - 1 && t == 0) rowptr[N_NODES] = N_EDGES;
    __syncthreads();
    for (int i = beg + t; i < end; i += 256) {
        int p = ebuf[i];
        int slot = atomicAdd(&cur[(p >> 17) & 127], 1);  // LDS atomic
        esrc[slot] = p & 0x1FFFF;                        // within-bucket 8KB region
    }
}

// ---------------- aggregate: 4 lanes per node, 16 nodes per wave, no shuffles ----------------
__global__ __launch_bounds__(256) void aggregate_kernel(
    const int* __restrict__ rowptr, const int* __restrict__ esrc,
    const float* __restrict__ inv, const unsigned short* __restrict__ hb,
    unsigned short* __restrict__ meanb, int n_nodes)
{
    int tid = threadIdx.x;
    int lane = tid & 63, wave = tid >> 6;
    int g = lane >> 2, q = lane & 3;
    int node = (blockIdx.x * 4 + wave) * 16 + g;
    if (node >= n_nodes) return;
    int beg = rowptr[node], end = rowptr[node + 1];
    float a0 = 0.f, a1 = 0.f, a2 = 0.f, a3 = 0.f;
    float a4 = 0.f, a5 = 0.f, a6 = 0.f, a7 = 0.f;
    int j = beg;
    for (; j + 1 < end; j += 2) {
        int s0 = esrc[j];
        int s1 = esrc[j + 1];
        uint4 u0 = *(const uint4*)(hb + s0 * 32 + q * 8);
        uint4 u1 = *(const uint4*)(hb + s1 * 32 + q * 8);
        a0 += bflo(u0.x); a1 += bfhi(u0.x);
        a2 += bflo(u0.y); a3 += bfhi(u0.y);
        a4 += bflo(u0.z); a5 += bfhi(u0.z);
        a6 += bflo(u0.w); a7 += bfhi(u0.w);
        a0 += bflo(u1.x); a1 += bfhi(u1.x);
        a2 += bflo(u1.y); a3 += bfhi(u1.y);
        a4 += bflo(u1.z); a5 += bfhi(u1.z);
        a6 += bflo(u1.w); a7 += bfhi(u1.w);
    }
    if (j < end) {
        int s = esrc[j];
        uint4 u = *(const uint4*)(hb + s * 32 + q * 8);
        a0 += bflo(u.x); a1 += bfhi(u.x);
        a2 += bflo(u.y); a3 += bfhi(u.y);
        a4 += bflo(u.z); a5 += bfhi(u.z);
        a6 += bflo(u.w); a7 += bfhi(u.w);
    }
    float iv = inv[node];
    uint4 o;
    o.x = (unsigned)f2bf(a0 * iv) | ((unsigned)f2bf(a1 * iv) << 16);
    o.y = (unsigned)f2bf(a2 * iv) | ((unsigned)f2bf(a3 * iv) << 16);
    o.z = (unsigned)f2bf(a4 * iv) | ((unsigned)f2bf(a5 * iv) << 16);
    o.w = (unsigned)f2bf(a6 * iv) | ((unsigned)f2bf(a7 * iv) << 16);
    *(uint4*)(meanb + node * 32 + q * 8) = o;
}

// ---------------- dense: out = relu(cat(mean,self) @ Wcat + b) via MFMA ----------------
__global__ __launch_bounds__(256) void dense_kernel(
    const unsigned short* __restrict__ meanb, const unsigned short* __restrict__ selfb,
    const unsigned short* __restrict__ Wcat, const float* __restrict__ bl,
    void* __restrict__ outp, int n_nodes, int out_f32)
{
    int tid = threadIdx.x;
    int lane = tid & 63, wave = tid >> 6;
    int l15 = lane & 15, quad = lane >> 4;

    s16x8 bf[2][2];
    #pragma unroll
    for (int kt = 0; kt < 2; kt++)
        #pragma unroll
        for (int nt = 0; nt < 2; nt++)
            #pragma unroll
            for (int j = 0; j < 8; j++) {
                int k = kt * 32 + quad * 8 + j;
                bf[kt][nt][j] = (short)Wcat[k * 32 + l15 + nt * 16];
            }
    float bias0 = bl[l15], bias1 = bl[l15 + 16];

    int ntiles = (n_nodes + 15) >> 4;
    for (int tile = blockIdx.x * 4 + wave; tile < ntiles; tile += gridDim.x * 4) {
        int node = tile * 16 + l15;
        int na = min(node, n_nodes - 1);
        s16x8 am = *(const s16x8*)(meanb + na * 32 + quad * 8);
        s16x8 as = *(const s16x8*)(selfb + na * 32 + quad * 8);
        f32x4 acc0 = {0.f, 0.f, 0.f, 0.f};
        f32x4 acc1 = {0.f, 0.f, 0.f, 0.f};
        acc0 = __builtin_amdgcn_mfma_f32_16x16x32_bf16(am, bf[0][0], acc0, 0, 0, 0);
        acc0 = __builtin_amdgcn_mfma_f32_16x16x32_bf16(as, bf[1][0], acc0, 0, 0, 0);
        acc1 = __builtin_amdgcn_mfma_f32_16x16x32_bf16(am, bf[0][1], acc1, 0, 0, 0);
        acc1 = __builtin_amdgcn_mfma_f32_16x16x32_bf16(as, bf[1][1], acc1, 0, 0, 0);
        #pragma unroll
        for (int r = 0; r < 4; r++) {
            int onode = tile * 16 + quad * 4 + r;
            if (onode < n_nodes) {
                float v0 = fmaxf(acc0[r] + bias0, 0.f);
                float v1 = fmaxf(acc1[r] + bias1, 0.f);
                if (out_f32) {
                    ((float*)outp)[onode * 32 + l15]      = v0;
                    ((float*)outp)[onode * 32 + l15 + 16] = v1;
                } else {
                    ((unsigned short*)outp)[onode * 32 + l15]      = f2bf(v0);
                    ((unsigned short*)outp)[onode * 32 + l15 + 16] = f2bf(v1);
                }
            }
        }
    }
}

// ---------------- output projection: first 1000 nodes, 32 -> 8 (fp32) ----------------
__global__ void out_proj_kernel(const float* __restrict__ h3,
                                const float* __restrict__ Wout,
                                const float* __restrict__ bout,
                                float* __restrict__ out) {
    __shared__ float sWo[256];
    __shared__ float sbo[8];
    int tid = threadIdx.x;
    sWo[tid] = Wout[tid];
    if (tid < 8) sbo[tid] = bout[tid];
    __syncthreads();
    int node = blockIdx.x * 32 + (tid >> 3);
    int c = tid & 7;
    if (node >= N_AGENTS) return;
    float o = sbo[c];
    const float* hr = h3 + node * 32;
    #pragma unroll
    for (int k = 0; k < 32; k++) o += hr[k] * sWo[(k << 3) + c];
    out[node * 8 + c] = o;
}

extern "C" void kernel_launch(void* const* d_in, const int* in_sizes, int n_in,
                              void* d_out, int out_size, void* d_ws, size_t ws_size,
                              hipStream_t stream) {
    const float* x   = (const float*)d_in[0];
    const int* ei    = (const int*)d_in[1];
    const float* Wl1 = (const float*)d_in[2];
    const float* bl1 = (const float*)d_in[3];
    const float* Wr1 = (const float*)d_in[4];
    const float* Wl2 = (const float*)d_in[5];
    const float* bl2 = (const float*)d_in[6];
    const float* Wr2 = (const float*)d_in[7];
    const float* Wl3 = (const float*)d_in[8];
    const float* bl3 = (const float*)d_in[9];
    const float* Wr3 = (const float*)d_in[10];
    const float* Wout = (const float*)d_in[11];
    const float* bout = (const float*)d_in[12];
    float* out = (float*)d_out;

    const int* src = ei;
    const int* dst = ei + N_EDGES;

    // workspace layout (16B-aligned regions; ebuf aliases meanb: ebuf dead
    // after bucket_csr_kernel, meanb first written by aggregate L1)
    char* ws = (char*)d_ws;
    int*   rowptr  = (int*)ws;                                 ws += (size_t)(N_NODES + 8) * 4;
    float* inv     = (float*)ws;                               ws += (size_t)N_NODES * 4;
    int*   partial = (int*)ws;                                 ws += (size_t)ABLK * NB * 4;
    int*   base    = (int*)ws;                                 ws += (size_t)ABLK * NB * 4;
    int*   bstart  = (int*)ws;                                 ws += 784 * 4;
    int*   esrc    = (int*)ws;                                 ws += (size_t)N_EDGES * 4;
    unsigned short* meanb = (unsigned short*)ws;               ws += (size_t)N_NODES * 32 * 2;
    unsigned short* hXb   = (unsigned short*)ws;               ws += (size_t)N_NODES * 32 * 2;
    unsigned short* hAb   = (unsigned short*)ws;               ws += (size_t)N_NODES * 32 * 2;
    unsigned short* hBb   = (unsigned short*)ws;               ws += (size_t)N_NODES * 32 * 2;
    unsigned short* Wcat  = (unsigned short*)ws;               ws += 3 * 2048 * 2;
    float* h3f     = (float*)ws;                               ws += (size_t)N_AGENTS * 32 * 4;
    int*   ebuf    = (int*)meanb;    // alias

    // ---- CSR build (no global atomics) + fused prep ----
    hist_prep_kernel<<<ABLK + CONV_BLOCKS + 24, 256, 0, stream>>>(
        dst, partial, x, hXb, Wl1, Wr1, Wl2, Wr2, Wl3, Wr3, Wcat);
    bucket_scan_kernel<<<1, 1024, 0, stream>>>(partial, base, bstart);
    bucket_scatter_kernel<<<ABLK, 256, 0, stream>>>(src, dst, base, ebuf);
    bucket_csr_kernel<<<NB, 256, 0, stream>>>(bstart, ebuf, rowptr, inv, esrc);

    // ---- layer 1 ----
    aggregate_kernel<<<(N_NODES + 63) / 64, 256, 0, stream>>>(rowptr, esrc, inv, hXb, meanb, N_NODES);
    dense_kernel<<<512, 256, 0, stream>>>(meanb, hXb, Wcat, bl1, hAb, N_NODES, 0);
    // ---- layer 2 ----
    aggregate_kernel<<<(N_NODES + 63) / 64, 256, 0, stream>>>(rowptr, esrc, inv, hAb, meanb, N_NODES);
    dense_kernel<<<512, 256, 0, stream>>>(meanb, hAb, Wcat + 2048, bl2, hBb, N_NODES, 0);
    // ---- layer 3: only nodes < N_AGENTS needed ----
    aggregate_kernel<<<(N_AGENTS + 63) / 64, 256, 0, stream>>>(rowptr, esrc, inv, hBb, meanb, N_AGENTS);
    dense_kernel<<<16, 256, 0, stream>>>(meanb, hBb, Wcat + 4096, bl3, h3f, N_AGENTS, 1);
    out_proj_kernel<<<(N_AGENTS + 31) / 32, 256, 0, stream>>>(h3f, Wout, bout, out);
}

// Round 9
// 226.518 us; speedup vs baseline: 1.3611x; 1.1044x over previous
//
#include <hip/hip_runtime.h>
#include <hip/hip_bf16.h>

#define N_NODES 100000
#define N_EDGES 1600000
#define N_AGENTS 1000

#define NB 782                 // buckets of 128 nodes (782*128 = 100096 >= 100000)
#define ABLK 512               // edge-chunk blocks for histogram/scatter
#define CHUNK (N_EDGES / ABLK) // 3125 exactly
#define CONV_BLOCKS 3125       // 800000 float4->ushort4 elements / 256

typedef short s16x8 __attribute__((ext_vector_type(8)));
typedef float f32x4 __attribute__((ext_vector_type(4)));

// float -> bf16 round-to-nearest-even
__device__ __forceinline__ unsigned short f2bf(float f) {
    unsigned u = __float_as_uint(f);
    u += 0x7fffu + ((u >> 16) & 1u);
    return (unsigned short)(u >> 16);
}
__device__ __forceinline__ float bflo(unsigned u) { return __uint_as_float(u << 16); }
__device__ __forceinline__ float bfhi(unsigned u) { return __uint_as_float(u & 0xffff0000u); }

// ---------------- A: bucket histogram (LDS atomics only) + fused prep ----------------
// partialT is bucket-major: partialT[t * ABLK + k]
__global__ __launch_bounds__(256) void hist_prep_kernel(
    const int* __restrict__ dst, int* __restrict__ partialT,
    const float* __restrict__ x, unsigned short* __restrict__ xb,
    const float* __restrict__ Wl1, const float* __restrict__ Wr1,
    const float* __restrict__ Wl2, const float* __restrict__ Wr2,
    const float* __restrict__ Wl3, const float* __restrict__ Wr3,
    unsigned short* __restrict__ Wcat)
{
    int b = blockIdx.x;
    if (b < ABLK) {
        __shared__ int hist[NB];
        for (int i = threadIdx.x; i < NB; i += 256) hist[i] = 0;
        __syncthreads();
        int beg = b * CHUNK;
        for (int e = beg + threadIdx.x; e < beg + CHUNK; e += 256)
            atomicAdd(&hist[dst[e] >> 7], 1);            // LDS atomic
        __syncthreads();
        for (int i = threadIdx.x; i < NB; i += 256) partialT[i * ABLK + b] = hist[i];
    } else if (b < ABLK + CONV_BLOCKS) {
        int i = (b - ABLK) * 256 + threadIdx.x;          // exact: 800000 elements
        float4 v = ((const float4*)x)[i];
        ((ushort4*)xb)[i] = make_ushort4(f2bf(v.x), f2bf(v.y), f2bf(v.z), f2bf(v.w));
    } else {
        int gid = (b - ABLK - CONV_BLOCKS) * 256 + threadIdx.x;
        if (gid >= 3 * 2048) return;
        int L = gid >> 11, idx = gid & 2047;
        int k = idx >> 5, n = idx & 31;
        const float* Wl = (L == 0) ? Wl1 : (L == 1) ? Wl2 : Wl3;
        const float* Wr = (L == 0) ? Wr1 : (L == 1) ? Wr2 : Wr3;
        float v = (k < 32) ? Wl[k * 32 + n] : Wr[(k - 32) * 32 + n];
        Wcat[gid] = f2bf(v);
    }
}

// ---------------- B1: per-bucket prefix over ABLK chunk-partials (1 wave/bucket) ----------------
__global__ __launch_bounds__(256) void bucket_prefix_kernel(
    const int* __restrict__ partialT, int* __restrict__ baseT, int* __restrict__ tot)
{
    int wave = threadIdx.x >> 6, lane = threadIdx.x & 63;
    int t = blockIdx.x * 4 + wave;
    if (t >= NB) return;
    const int4* p = (const int4*)(partialT + (size_t)t * ABLK);
    int4 u0 = p[lane * 2], u1 = p[lane * 2 + 1];        // 8 partials per lane
    int v0 = u0.x, v1 = u0.y, v2 = u0.z, v3 = u0.w;
    int v4 = u1.x, v5 = u1.y, v6 = u1.z, v7 = u1.w;
    int p0 = 0, p1 = v0, p2 = p1 + v1, p3 = p2 + v2;
    int p4 = p3 + v3, p5 = p4 + v4, p6 = p5 + v5, p7 = p6 + v6;
    int s = p7 + v7;                                     // lane total
    int x = s;                                           // wave inclusive scan
    #pragma unroll
    for (int off = 1; off < 64; off <<= 1) {
        int y = __shfl_up(x, off);
        if (lane >= off) x += y;
    }
    int excl = x - s;                                    // exclusive prefix of lane sums
    int4* q = (int4*)(baseT + (size_t)t * ABLK);
    q[lane * 2]     = make_int4(excl + p0, excl + p1, excl + p2, excl + p3);
    q[lane * 2 + 1] = make_int4(excl + p4, excl + p5, excl + p6, excl + p7);
    if (lane == 63) tot[t] = x;
}

// ---------------- B2: exclusive scan of bucket totals -> bucket starts ----------------
__global__ __launch_bounds__(1024) void total_scan_kernel(
    const int* __restrict__ tot, int* __restrict__ bstart)
{
    __shared__ int tmp[1024];
    int t = threadIdx.x;
    int v = (t < NB) ? tot[t] : 0;
    tmp[t] = v;
    __syncthreads();
    for (int off = 1; off < 1024; off <<= 1) {
        int u = (t >= off) ? tmp[t - off] : 0;
        __syncthreads();
        tmp[t] += u;
        __syncthreads();
    }
    if (t < NB) {
        bstart[t] = tmp[t] - v;
        if (t == NB - 1) bstart[NB] = tmp[t];            // == N_EDGES
    }
}

// ---------------- C: scatter edges into buckets, packed (src | local_node<<17) ----------------
__global__ __launch_bounds__(256) void bucket_scatter_kernel(
    const int* __restrict__ src, const int* __restrict__ dst,
    const int* __restrict__ baseT, const int* __restrict__ bstart,
    int* __restrict__ ebuf)
{
    __shared__ int cur[NB];
    int b = blockIdx.x;
    for (int i = threadIdx.x; i < NB; i += 256)
        cur[i] = bstart[i] + baseT[(size_t)i * ABLK + b];
    __syncthreads();
    int beg = b * CHUNK;
    for (int e = beg + threadIdx.x; e < beg + CHUNK; e += 256) {
        int d = dst[e];
        int slot = atomicAdd(&cur[d >> 7], 1);           // LDS atomic
        ebuf[slot] = src[e] | ((d & 127) << 17);         // src < 2^17
    }
}

// ---------------- D: per-bucket CSR finalize: rowptr, inv, node-exact esrc ----------------
__global__ __launch_bounds__(256) void bucket_csr_kernel(
    const int* __restrict__ bstart, const int* __restrict__ ebuf,
    int* __restrict__ rowptr, float* __restrict__ inv, int* __restrict__ esrc)
{
    __shared__ int hist[128], cur[128], tmp[256];
    int b = blockIdx.x;
    int t = threadIdx.x;
    int beg = bstart[b], end = bstart[b + 1];
    if (t < 128) hist[t] = 0;
    __syncthreads();
    for (int i = beg + t; i < end; i += 256)
        atomicAdd(&hist[(ebuf[i] >> 17) & 127], 1);      // LDS atomic
    __syncthreads();
    int v = (t < 128) ? hist[t] : 0;
    tmp[t] = v;
    __syncthreads();
    for (int off = 1; off < 256; off <<= 1) {
        int u = (t >= off) ? tmp[t - off] : 0;
        __syncthreads();
        tmp[t] += u;
        __syncthreads();
    }
    int excl = tmp[t] - v;                               // exclusive within bucket
    int node = b * 128 + t;
    if (t < 128 && node < N_NODES) {
        rowptr[node] = beg + excl;
        inv[node] = 1.0f / fmaxf((float)v, 1.0f);
        cur[t] = beg + excl;
    }
    if (b == NB - 1 && t == 0) rowptr[N_NODES] = N_EDGES;
    __syncthreads();
    for (int i = beg + t; i < end; i += 256) {
        int p = ebuf[i];
        int slot = atomicAdd(&cur[(p >> 17) & 127], 1);  // LDS atomic
        esrc[slot] = p & 0x1FFFF;                        // within-bucket 8KB region
    }
}

// ---------------- aggregate: 4 lanes per node, 16 nodes per wave, no shuffles ----------------
__global__ __launch_bounds__(256) void aggregate_kernel(
    const int* __restrict__ rowptr, const int* __restrict__ esrc,
    const float* __restrict__ inv, const unsigned short* __restrict__ hb,
    unsigned short* __restrict__ meanb, int n_nodes)
{
    int tid = threadIdx.x;
    int lane = tid & 63, wave = tid >> 6;
    int g = lane >> 2, q = lane & 3;
    int node = (blockIdx.x * 4 + wave) * 16 + g;
    if (node >= n_nodes) return;
    int beg = rowptr[node], end = rowptr[node + 1];
    float a0 = 0.f, a1 = 0.f, a2 = 0.f, a3 = 0.f;
    float a4 = 0.f, a5 = 0.f, a6 = 0.f, a7 = 0.f;
    int j = beg;
    for (; j + 1 < end; j += 2) {
        int s0 = esrc[j];
        int s1 = esrc[j + 1];
        uint4 u0 = *(const uint4*)(hb + s0 * 32 + q * 8);
        uint4 u1 = *(const uint4*)(hb + s1 * 32 + q * 8);
        a0 += bflo(u0.x); a1 += bfhi(u0.x);
        a2 += bflo(u0.y); a3 += bfhi(u0.y);
        a4 += bflo(u0.z); a5 += bfhi(u0.z);
        a6 += bflo(u0.w); a7 += bfhi(u0.w);
        a0 += bflo(u1.x); a1 += bfhi(u1.x);
        a2 += bflo(u1.y); a3 += bfhi(u1.y);
        a4 += bflo(u1.z); a5 += bfhi(u1.z);
        a6 += bflo(u1.w); a7 += bfhi(u1.w);
    }
    if (j < end) {
        int s = esrc[j];
        uint4 u = *(const uint4*)(hb + s * 32 + q * 8);
        a0 += bflo(u.x); a1 += bfhi(u.x);
        a2 += bflo(u.y); a3 += bfhi(u.y);
        a4 += bflo(u.z); a5 += bfhi(u.z);
        a6 += bflo(u.w); a7 += bfhi(u.w);
    }
    float iv = inv[node];
    uint4 o;
    o.x = (unsigned)f2bf(a0 * iv) | ((unsigned)f2bf(a1 * iv) << 16);
    o.y = (unsigned)f2bf(a2 * iv) | ((unsigned)f2bf(a3 * iv) << 16);
    o.z = (unsigned)f2bf(a4 * iv) | ((unsigned)f2bf(a5 * iv) << 16);
    o.w = (unsigned)f2bf(a6 * iv) | ((unsigned)f2bf(a7 * iv) << 16);
    *(uint4*)(meanb + node * 32 + q * 8) = o;
}

// ---------------- dense: out = relu(cat(mean,self) @ Wcat + b) via MFMA ----------------
__global__ __launch_bounds__(256) void dense_kernel(
    const unsigned short* __restrict__ meanb, const unsigned short* __restrict__ selfb,
    const unsigned short* __restrict__ Wcat, const float* __restrict__ bl,
    void* __restrict__ outp, int n_nodes, int out_f32)
{
    int tid = threadIdx.x;
    int lane = tid & 63, wave = tid >> 6;
    int l15 = lane & 15, quad = lane >> 4;

    s16x8 bf[2][2];
    #pragma unroll
    for (int kt = 0; kt < 2; kt++)
        #pragma unroll
        for (int nt = 0; nt < 2; nt++)
            #pragma unroll
            for (int j = 0; j < 8; j++) {
                int k = kt * 32 + quad * 8 + j;
                bf[kt][nt][j] = (short)Wcat[k * 32 + l15 + nt * 16];
            }
    float bias0 = bl[l15], bias1 = bl[l15 + 16];

    int ntiles = (n_nodes + 15) >> 4;
    for (int tile = blockIdx.x * 4 + wave; tile < ntiles; tile += gridDim.x * 4) {
        int node = tile * 16 + l15;
        int na = min(node, n_nodes - 1);
        s16x8 am = *(const s16x8*)(meanb + na * 32 + quad * 8);
        s16x8 as = *(const s16x8*)(selfb + na * 32 + quad * 8);
        f32x4 acc0 = {0.f, 0.f, 0.f, 0.f};
        f32x4 acc1 = {0.f, 0.f, 0.f, 0.f};
        acc0 = __builtin_amdgcn_mfma_f32_16x16x32_bf16(am, bf[0][0], acc0, 0, 0, 0);
        acc0 = __builtin_amdgcn_mfma_f32_16x16x32_bf16(as, bf[1][0], acc0, 0, 0, 0);
        acc1 = __builtin_amdgcn_mfma_f32_16x16x32_bf16(am, bf[0][1], acc1, 0, 0, 0);
        acc1 = __builtin_amdgcn_mfma_f32_16x16x32_bf16(as, bf[1][1], acc1, 0, 0, 0);
        #pragma unroll
        for (int r = 0; r < 4; r++) {
            int onode = tile * 16 + quad * 4 + r;
            if (onode < n_nodes) {
                float v0 = fmaxf(acc0[r] + bias0, 0.f);
                float v1 = fmaxf(acc1[r] + bias1, 0.f);
                if (out_f32) {
                    ((float*)outp)[onode * 32 + l15]      = v0;
                    ((float*)outp)[onode * 32 + l15 + 16] = v1;
                } else {
                    ((unsigned short*)outp)[onode * 32 + l15]      = f2bf(v0);
                    ((unsigned short*)outp)[onode * 32 + l15 + 16] = f2bf(v1);
                }
            }
        }
    }
}

// ---------------- output projection: first 1000 nodes, 32 -> 8 (fp32) ----------------
__global__ void out_proj_kernel(const float* __restrict__ h3,
                                const float* __restrict__ Wout,
                                const float* __restrict__ bout,
                                float* __restrict__ out) {
    __shared__ float sWo[256];
    __shared__ float sbo[8];
    int tid = threadIdx.x;
    sWo[tid] = Wout[tid];
    if (tid < 8) sbo[tid] = bout[tid];
    __syncthreads();
    int node = blockIdx.x * 32 + (tid >> 3);
    int c = tid & 7;
    if (node >= N_AGENTS) return;
    float o = sbo[c];
    const float* hr = h3 + node * 32;
    #pragma unroll
    for (int k = 0; k < 32; k++) o += hr[k] * sWo[(k << 3) + c];
    out[node * 8 + c] = o;
}

extern "C" void kernel_launch(void* const* d_in, const int* in_sizes, int n_in,
                              void* d_out, int out_size, void* d_ws, size_t ws_size,
                              hipStream_t stream) {
    const float* x   = (const float*)d_in[0];
    const int* ei    = (const int*)d_in[1];
    const float* Wl1 = (const float*)d_in[2];
    const float* bl1 = (const float*)d_in[3];
    const float* Wr1 = (const float*)d_in[4];
    const float* Wl2 = (const float*)d_in[5];
    const float* bl2 = (const float*)d_in[6];
    const float* Wr2 = (const float*)d_in[7];
    const float* Wl3 = (const float*)d_in[8];
    const float* bl3 = (const float*)d_in[9];
    const float* Wr3 = (const float*)d_in[10];
    const float* Wout = (const float*)d_in[11];
    const float* bout = (const float*)d_in[12];
    float* out = (float*)d_out;

    const int* src = ei;
    const int* dst = ei + N_EDGES;

    // workspace layout (ebuf aliases meanb: ebuf dead after bucket_csr_kernel,
    // meanb first written by aggregate L1)
    char* ws = (char*)d_ws;
    int*   rowptr   = (int*)ws;                                ws += (size_t)(N_NODES + 8) * 4;
    float* inv      = (float*)ws;                              ws += (size_t)N_NODES * 4;
    int*   partialT = (int*)ws;                                ws += (size_t)NB * ABLK * 4;
    int*   baseT    = (int*)ws;                                ws += (size_t)NB * ABLK * 4;
    int*   tot      = (int*)ws;                                ws += 784 * 4;
    int*   bstart   = (int*)ws;                                ws += 784 * 4;
    int*   esrc     = (int*)ws;                                ws += (size_t)N_EDGES * 4;
    unsigned short* meanb = (unsigned short*)ws;               ws += (size_t)N_NODES * 32 * 2;
    unsigned short* hXb   = (unsigned short*)ws;               ws += (size_t)N_NODES * 32 * 2;
    unsigned short* hAb   = (unsigned short*)ws;               ws += (size_t)N_NODES * 32 * 2;
    unsigned short* hBb   = (unsigned short*)ws;               ws += (size_t)N_NODES * 32 * 2;
    unsigned short* Wcat  = (unsigned short*)ws;               ws += 3 * 2048 * 2;
    float* h3f      = (float*)ws;                              ws += (size_t)N_AGENTS * 32 * 4;
    int*   ebuf     = (int*)meanb;    // alias

    // ---- CSR build (no global atomics) + fused prep ----
    hist_prep_kernel<<<ABLK + CONV_BLOCKS + 24, 256, 0, stream>>>(
        dst, partialT, x, hXb, Wl1, Wr1, Wl2, Wr2, Wl3, Wr3, Wcat);
    bucket_prefix_kernel<<<(NB + 3) / 4, 256, 0, stream>>>(partialT, baseT, tot);
    total_scan_kernel<<<1, 1024, 0, stream>>>(tot, bstart);
    bucket_scatter_kernel<<<ABLK, 256, 0, stream>>>(src, dst, baseT, bstart, ebuf);
    bucket_csr_kernel<<<NB, 256, 0, stream>>>(bstart, ebuf, rowptr, inv, esrc);

    // ---- layer 1 ----
    aggregate_kernel<<<(N_NODES + 63) / 64, 256, 0, stream>>>(rowptr, esrc, inv, hXb, meanb, N_NODES);
    dense_kernel<<<512, 256, 0, stream>>>(meanb, hXb, Wcat, bl1, hAb, N_NODES, 0);
    // ---- layer 2 ----
    aggregate_kernel<<<(N_NODES + 63) / 64, 256, 0, stream>>>(rowptr, esrc, inv, hAb, meanb, N_NODES);
    dense_kernel<<<512, 256, 0, stream>>>(meanb, hAb, Wcat + 2048, bl2, hBb, N_NODES, 0);
    // ---- layer 3: only nodes < N_AGENTS needed ----
    aggregate_kernel<<<(N_AGENTS + 63) / 64, 256, 0, stream>>>(rowptr, esrc, inv, hBb, meanb, N_AGENTS);
    dense_kernel<<<16, 256, 0, stream>>>(meanb, hBb, Wcat + 4096, bl3, h3f, N_AGENTS, 1);
    out_proj_kernel<<<(N_AGENTS + 31) / 32, 256, 0, stream>>>(h3f, Wout, bout, out);
}

// Round 10
// 213.064 us; speedup vs baseline: 1.4471x; 1.0631x over previous
//
#include <hip/hip_runtime.h>
#include <hip/hip_bf16.h>

#define N_NODES 100000
#define N_EDGES 1600000
#define N_AGENTS 1000

#define NB 782                 // buckets of 128 nodes (782*128 = 100096 >= 100000)
#define ABLK 512               // edge-chunk blocks for histogram/scatter
#define CHUNK (N_EDGES / ABLK) // 3125 exactly
#define CONV_BLOCKS 3125       // 800000 float4->ushort4 elements / 256

typedef short s16x8 __attribute__((ext_vector_type(8)));
typedef float f32x4 __attribute__((ext_vector_type(4)));

// float -> bf16 round-to-nearest-even
__device__ __forceinline__ unsigned short f2bf(float f) {
    unsigned u = __float_as_uint(f);
    u += 0x7fffu + ((u >> 16) & 1u);
    return (unsigned short)(u >> 16);
}
__device__ __forceinline__ float bflo(unsigned u) { return __uint_as_float(u << 16); }
__device__ __forceinline__ float bfhi(unsigned u) { return __uint_as_float(u & 0xffff0000u); }

// ---------------- A: bucket histogram (LDS atomics only) + fused prep ----------------
// partialT is bucket-major: partialT[t * ABLK + k]
__global__ __launch_bounds__(256) void hist_prep_kernel(
    const int* __restrict__ dst, int* __restrict__ partialT,
    const float* __restrict__ x, unsigned short* __restrict__ xb,
    const float* __restrict__ Wl1, const float* __restrict__ Wr1,
    const float* __restrict__ Wl2, const float* __restrict__ Wr2,
    const float* __restrict__ Wl3, const float* __restrict__ Wr3,
    unsigned short* __restrict__ Wcat)
{
    int b = blockIdx.x;
    if (b < ABLK) {
        __shared__ int hist[NB];
        for (int i = threadIdx.x; i < NB; i += 256) hist[i] = 0;
        __syncthreads();
        int beg = b * CHUNK;
        for (int e = beg + threadIdx.x; e < beg + CHUNK; e += 256)
            atomicAdd(&hist[dst[e] >> 7], 1);            // LDS atomic
        __syncthreads();
        for (int i = threadIdx.x; i < NB; i += 256) partialT[i * ABLK + b] = hist[i];
    } else if (b < ABLK + CONV_BLOCKS) {
        int i = (b - ABLK) * 256 + threadIdx.x;          // exact: 800000 elements
        float4 v = ((const float4*)x)[i];
        ((ushort4*)xb)[i] = make_ushort4(f2bf(v.x), f2bf(v.y), f2bf(v.z), f2bf(v.w));
    } else {
        int gid = (b - ABLK - CONV_BLOCKS) * 256 + threadIdx.x;
        if (gid >= 3 * 2048) return;
        int L = gid >> 11, idx = gid & 2047;
        int k = idx >> 5, n = idx & 31;
        const float* Wl = (L == 0) ? Wl1 : (L == 1) ? Wl2 : Wl3;
        const float* Wr = (L == 0) ? Wr1 : (L == 1) ? Wr2 : Wr3;
        float v = (k < 32) ? Wl[k * 32 + n] : Wr[(k - 32) * 32 + n];
        Wcat[gid] = f2bf(v);
    }
}

// ---------------- B1: per-bucket prefix over ABLK chunk-partials (1 wave/bucket) ----------------
__global__ __launch_bounds__(256) void bucket_prefix_kernel(
    const int* __restrict__ partialT, int* __restrict__ baseT, int* __restrict__ tot)
{
    int wave = threadIdx.x >> 6, lane = threadIdx.x & 63;
    int t = blockIdx.x * 4 + wave;
    if (t >= NB) return;
    const int4* p = (const int4*)(partialT + (size_t)t * ABLK);
    int4 u0 = p[lane * 2], u1 = p[lane * 2 + 1];        // 8 partials per lane
    int v0 = u0.x, v1 = u0.y, v2 = u0.z, v3 = u0.w;
    int v4 = u1.x, v5 = u1.y, v6 = u1.z, v7 = u1.w;
    int p0 = 0, p1 = v0, p2 = p1 + v1, p3 = p2 + v2;
    int p4 = p3 + v3, p5 = p4 + v4, p6 = p5 + v5, p7 = p6 + v6;
    int s = p7 + v7;                                     // lane total
    int x = s;                                           // wave inclusive scan
    #pragma unroll
    for (int off = 1; off < 64; off <<= 1) {
        int y = __shfl_up(x, off);
        if (lane >= off) x += y;
    }
    int excl = x - s;                                    // exclusive prefix of lane sums
    int4* q = (int4*)(baseT + (size_t)t * ABLK);
    q[lane * 2]     = make_int4(excl + p0, excl + p1, excl + p2, excl + p3);
    q[lane * 2 + 1] = make_int4(excl + p4, excl + p5, excl + p6, excl + p7);
    if (lane == 63) tot[t] = x;
}

// ---------------- B2: exclusive scan of bucket totals -> bucket starts ----------------
__global__ __launch_bounds__(1024) void total_scan_kernel(
    const int* __restrict__ tot, int* __restrict__ bstart)
{
    __shared__ int tmp[1024];
    int t = threadIdx.x;
    int v = (t < NB) ? tot[t] : 0;
    tmp[t] = v;
    __syncthreads();
    for (int off = 1; off < 1024; off <<= 1) {
        int u = (t >= off) ? tmp[t - off] : 0;
        __syncthreads();
        tmp[t] += u;
        __syncthreads();
    }
    if (t < NB) {
        bstart[t] = tmp[t] - v;
        if (t == NB - 1) bstart[NB] = tmp[t];            // == N_EDGES
    }
}

// ---------------- C: scatter edges into buckets, packed (src | local_node<<17) ----------------
__global__ __launch_bounds__(256) void bucket_scatter_kernel(
    const int* __restrict__ src, const int* __restrict__ dst,
    const int* __restrict__ baseT, const int* __restrict__ bstart,
    int* __restrict__ ebuf)
{
    __shared__ int cur[NB];
    int b = blockIdx.x;
    for (int i = threadIdx.x; i < NB; i += 256)
        cur[i] = bstart[i] + baseT[(size_t)i * ABLK + b];
    __syncthreads();
    int beg = b * CHUNK;
    for (int e = beg + threadIdx.x; e < beg + CHUNK; e += 256) {
        int d = dst[e];
        int slot = atomicAdd(&cur[d >> 7], 1);           // LDS atomic
        ebuf[slot] = src[e] | ((d & 127) << 17);         // src < 2^17
    }
}

// ---------------- D: per-bucket CSR finalize: rowptr, inv, node-exact esrc ----------------
__global__ __launch_bounds__(256) void bucket_csr_kernel(
    const int* __restrict__ bstart, const int* __restrict__ ebuf,
    int* __restrict__ rowptr, float* __restrict__ inv, int* __restrict__ esrc)
{
    __shared__ int hist[128], cur[128], tmp[256];
    int b = blockIdx.x;
    int t = threadIdx.x;
    int beg = bstart[b], end = bstart[b + 1];
    if (t < 128) hist[t] = 0;
    __syncthreads();
    for (int i = beg + t; i < end; i += 256)
        atomicAdd(&hist[(ebuf[i] >> 17) & 127], 1);      // LDS atomic
    __syncthreads();
    int v = (t < 128) ? hist[t] : 0;
    tmp[t] = v;
    __syncthreads();
    for (int off = 1; off < 256; off <<= 1) {
        int u = (t >= off) ? tmp[t - off] : 0;
        __syncthreads();
        tmp[t] += u;
        __syncthreads();
    }
    int excl = tmp[t] - v;                               // exclusive within bucket
    int node = b * 128 + t;
    if (t < 128 && node < N_NODES) {
        rowptr[node] = beg + excl;
        inv[node] = 1.0f / fmaxf((float)v, 1.0f);
        cur[t] = beg + excl;
    }
    if (b == NB - 1 && t == 0) rowptr[N_NODES] = N_EDGES;
    __syncthreads();
    for (int i = beg + t; i < end; i += 256) {
        int p = ebuf[i];
        int slot = atomicAdd(&cur[(p >> 17) & 127], 1);  // LDS atomic
        esrc[slot] = p & 0x1FFFF;                        // within-bucket 8KB region
    }
}

// ---------------- fused layer: aggregate (regs) -> LDS -> MFMA dense -> out ----------------
// Block = 64 nodes. Phase 1 (r7 pattern): 4 lanes/node, lane owns 8 channels,
// fp32 acc over all neighbors; pack bf16 mean into LDS (stride 40 shorts:
// 16B-aligned rows, 2-way bank aliasing = free). Phase 2: wave w MFMAs nodes
// [w*16, w*16+16): A-frags from LDS mean + global self; weights staged in LDS.
// final=1: layer-3 + 32->8 output projection through a second LDS stage.
__global__ __launch_bounds__(256) void sage_fused_kernel(
    const int* __restrict__ rowptr, const int* __restrict__ esrc,
    const float* __restrict__ inv, const unsigned short* __restrict__ hb,
    const unsigned short* __restrict__ Wcat, const float* __restrict__ bl,
    const float* __restrict__ Wout, const float* __restrict__ bout,
    void* __restrict__ outp, int n_nodes, int final)
{
    __shared__ unsigned short sW[2048];      // 64k x 32n bf16 layer weights
    __shared__ float sb[32];
    __shared__ unsigned short smean[64 * 40];
    __shared__ float sh3[64 * 33];
    __shared__ float sWo[256];
    __shared__ float sbo[8];

    int tid = threadIdx.x;
    ((uint4*)sW)[tid] = ((const uint4*)Wcat)[tid];       // 256 x 16B = 4KB exact
    if (tid < 32) sb[tid] = bl[tid];
    if (final) {
        sWo[tid] = Wout[tid];                            // 256 exact
        if (tid < 8) sbo[tid] = bout[tid];
    }

    int lane = tid & 63, wave = tid >> 6;

    // ---- phase 1: aggregate ----
    int g = lane >> 2, q = lane & 3;
    int nodeA = blockIdx.x * 64 + wave * 16 + g;
    int beg = 0, end = 0;
    if (nodeA < n_nodes) { beg = rowptr[nodeA]; end = rowptr[nodeA + 1]; }
    float a0 = 0.f, a1 = 0.f, a2 = 0.f, a3 = 0.f;
    float a4 = 0.f, a5 = 0.f, a6 = 0.f, a7 = 0.f;
    int j = beg;
    for (; j + 1 < end; j += 2) {
        int s0 = esrc[j];
        int s1 = esrc[j + 1];
        uint4 u0 = *(const uint4*)(hb + s0 * 32 + q * 8);
        uint4 u1 = *(const uint4*)(hb + s1 * 32 + q * 8);
        a0 += bflo(u0.x); a1 += bfhi(u0.x);
        a2 += bflo(u0.y); a3 += bfhi(u0.y);
        a4 += bflo(u0.z); a5 += bfhi(u0.z);
        a6 += bflo(u0.w); a7 += bfhi(u0.w);
        a0 += bflo(u1.x); a1 += bfhi(u1.x);
        a2 += bflo(u1.y); a3 += bfhi(u1.y);
        a4 += bflo(u1.z); a5 += bfhi(u1.z);
        a6 += bflo(u1.w); a7 += bfhi(u1.w);
    }
    if (j < end) {
        int s = esrc[j];
        uint4 u = *(const uint4*)(hb + s * 32 + q * 8);
        a0 += bflo(u.x); a1 += bfhi(u.x);
        a2 += bflo(u.y); a3 += bfhi(u.y);
        a4 += bflo(u.z); a5 += bfhi(u.z);
        a6 += bflo(u.w); a7 += bfhi(u.w);
    }
    float iv = (nodeA < n_nodes) ? inv[nodeA] : 0.f;
    uint4 o;
    o.x = (unsigned)f2bf(a0 * iv) | ((unsigned)f2bf(a1 * iv) << 16);
    o.y = (unsigned)f2bf(a2 * iv) | ((unsigned)f2bf(a3 * iv) << 16);
    o.z = (unsigned)f2bf(a4 * iv) | ((unsigned)f2bf(a5 * iv) << 16);
    o.w = (unsigned)f2bf(a6 * iv) | ((unsigned)f2bf(a7 * iv) << 16);
    int mrow = wave * 16 + g;
    *(uint4*)&smean[mrow * 40 + q * 8] = o;
    __syncthreads();

    // ---- phase 2: dense via MFMA ----
    int l15 = lane & 15, quad = lane >> 4;
    s16x8 bf_[2][2];
    #pragma unroll
    for (int kt = 0; kt < 2; kt++)
        #pragma unroll
        for (int nt = 0; nt < 2; nt++)
            #pragma unroll
            for (int jj = 0; jj < 8; jj++) {
                int k = kt * 32 + quad * 8 + jj;
                bf_[kt][nt][jj] = (short)sW[k * 32 + l15 + nt * 16];
            }
    float bias0 = sb[l15], bias1 = sb[l15 + 16];

    int tilebase = blockIdx.x * 64 + wave * 16;
    int nodeD = tilebase + l15;
    int na = min(nodeD, n_nodes - 1);
    s16x8 am = *(const s16x8*)&smean[(wave * 16 + l15) * 40 + quad * 8];
    s16x8 as = *(const s16x8*)(hb + (size_t)na * 32 + quad * 8);
    f32x4 acc0 = {0.f, 0.f, 0.f, 0.f};
    f32x4 acc1 = {0.f, 0.f, 0.f, 0.f};
    acc0 = __builtin_amdgcn_mfma_f32_16x16x32_bf16(am, bf_[0][0], acc0, 0, 0, 0);
    acc0 = __builtin_amdgcn_mfma_f32_16x16x32_bf16(as, bf_[1][0], acc0, 0, 0, 0);
    acc1 = __builtin_amdgcn_mfma_f32_16x16x32_bf16(am, bf_[0][1], acc1, 0, 0, 0);
    acc1 = __builtin_amdgcn_mfma_f32_16x16x32_bf16(as, bf_[1][1], acc1, 0, 0, 0);

    if (!final) {
        #pragma unroll
        for (int r = 0; r < 4; r++) {
            int onode = tilebase + quad * 4 + r;
            if (onode < n_nodes) {
                ((unsigned short*)outp)[onode * 32 + l15]      = f2bf(fmaxf(acc0[r] + bias0, 0.f));
                ((unsigned short*)outp)[onode * 32 + l15 + 16] = f2bf(fmaxf(acc1[r] + bias1, 0.f));
            }
        }
    } else {
        #pragma unroll
        for (int r = 0; r < 4; r++) {
            int row = wave * 16 + quad * 4 + r;
            sh3[row * 33 + l15]      = fmaxf(acc0[r] + bias0, 0.f);
            sh3[row * 33 + l15 + 16] = fmaxf(acc1[r] + bias1, 0.f);
        }
        __syncthreads();
        // 64 nodes x 8 out-channels = 512 outputs, 2 per thread
        #pragma unroll
        for (int i = tid; i < 512; i += 256) {
            int ln = i >> 3, c = i & 7;
            int gn = blockIdx.x * 64 + ln;
            if (gn < N_AGENTS) {
                float ov = sbo[c];
                #pragma unroll
                for (int k = 0; k < 32; k++) ov += sh3[ln * 33 + k] * sWo[k * 8 + c];
                ((float*)outp)[gn * 8 + c] = ov;
            }
        }
    }
}

extern "C" void kernel_launch(void* const* d_in, const int* in_sizes, int n_in,
                              void* d_out, int out_size, void* d_ws, size_t ws_size,
                              hipStream_t stream) {
    const float* x   = (const float*)d_in[0];
    const int* ei    = (const int*)d_in[1];
    const float* Wl1 = (const float*)d_in[2];
    const float* bl1 = (const float*)d_in[3];
    const float* Wr1 = (const float*)d_in[4];
    const float* Wl2 = (const float*)d_in[5];
    const float* bl2 = (const float*)d_in[6];
    const float* Wr2 = (const float*)d_in[7];
    const float* Wl3 = (const float*)d_in[8];
    const float* bl3 = (const float*)d_in[9];
    const float* Wr3 = (const float*)d_in[10];
    const float* Wout = (const float*)d_in[11];
    const float* bout = (const float*)d_in[12];
    float* out = (float*)d_out;

    const int* src = ei;
    const int* dst = ei + N_EDGES;

    // workspace layout (ebuf aliases hAb: ebuf dead after bucket_csr_kernel,
    // hAb first written by fused layer 1)
    char* ws = (char*)d_ws;
    int*   rowptr   = (int*)ws;                                ws += (size_t)(N_NODES + 8) * 4;
    float* inv      = (float*)ws;                              ws += (size_t)N_NODES * 4;
    int*   partialT = (int*)ws;                                ws += (size_t)NB * ABLK * 4;
    int*   baseT    = (int*)ws;                                ws += (size_t)NB * ABLK * 4;
    int*   tot      = (int*)ws;                                ws += 784 * 4;
    int*   bstart   = (int*)ws;                                ws += 784 * 4;
    int*   esrc     = (int*)ws;                                ws += (size_t)N_EDGES * 4;
    unsigned short* hXb   = (unsigned short*)ws;               ws += (size_t)N_NODES * 32 * 2;
    unsigned short* hAb   = (unsigned short*)ws;               ws += (size_t)N_NODES * 32 * 2;
    unsigned short* hBb   = (unsigned short*)ws;               ws += (size_t)N_NODES * 32 * 2;
    unsigned short* Wcat  = (unsigned short*)ws;               ws += 3 * 2048 * 2;
    int*   ebuf     = (int*)hAb;    // alias

    // ---- CSR build (no global atomics) + fused prep ----
    hist_prep_kernel<<<ABLK + CONV_BLOCKS + 24, 256, 0, stream>>>(
        dst, partialT, x, hXb, Wl1, Wr1, Wl2, Wr2, Wl3, Wr3, Wcat);
    bucket_prefix_kernel<<<(NB + 3) / 4, 256, 0, stream>>>(partialT, baseT, tot);
    total_scan_kernel<<<1, 1024, 0, stream>>>(tot, bstart);
    bucket_scatter_kernel<<<ABLK, 256, 0, stream>>>(src, dst, baseT, bstart, ebuf);
    bucket_csr_kernel<<<NB, 256, 0, stream>>>(bstart, ebuf, rowptr, inv, esrc);

    // ---- fused layers ----
    sage_fused_kernel<<<(N_NODES + 63) / 64, 256, 0, stream>>>(
        rowptr, esrc, inv, hXb, Wcat, bl1, Wout, bout, hAb, N_NODES, 0);
    sage_fused_kernel<<<(N_NODES + 63) / 64, 256, 0, stream>>>(
        rowptr, esrc, inv, hAb, Wcat + 2048, bl2, Wout, bout, hBb, N_NODES, 0);
    sage_fused_kernel<<<(N_AGENTS + 63) / 64, 256, 0, stream>>>(
        rowptr, esrc, inv, hBb, Wcat + 4096, bl3, Wout, bout, out, N_AGENTS, 1);
}